// Round 1
// baseline (421.322 us; speedup 1.0000x reference)
//
#include <hip/hip_runtime.h>
#include <hip/hip_bf16.h>

#define N_IMG 64
#define C_DIM 512
#define L_DIM 1024
#define KK 64
#define KG 65

// ---------------- Stage 1: norms + logits + softmax -> a' = a * invnorm ----------------
// Grid: (16 l-blocks, 64 images), Block: 512 (8 waves). Wave w owns k in {w, w+8, ...}.
__global__ __launch_bounds__(512) void k_stage1(
    const float* __restrict__ x, const float* __restrict__ conv_w,
    const float* __restrict__ conv_b, float* __restrict__ aP,
    float* __restrict__ asum_part)
{
    __shared__ float xs[128 * 64];    // [c within chunk][l]  32 KB
    __shared__ float lg[KG * 64];     // logits then exp      16.6 KB
    __shared__ float psum[8 * 64];    // sumsq partials
    __shared__ float invl[64];
    __shared__ float rsl[64];

    const int lb   = blockIdx.x;          // 0..15
    const int n    = blockIdx.y;          // 0..63
    const int t    = threadIdx.x;         // 0..511
    const int lane = t & 63;
    const int w    = t >> 6;              // wave 0..7
    const int l0   = lb * 64;

    const int nk = (w == 0) ? 9 : 8;      // wave 0 also owns ghost k=64
    float acc[9];
#pragma unroll
    for (int j = 0; j < 9; ++j) acc[j] = 0.f;
    float ss = 0.f;

    for (int ch = 0; ch < 4; ++ch) {
        __syncthreads();
        // load chunk: c in [ch*128, ch*128+128), coalesced along l
#pragma unroll
        for (int i = 0; i < 16; ++i) {
            int idx = i * 512 + t;
            int cc  = idx >> 6;       // 0..127
            int ll  = idx & 63;
            xs[idx] = x[((size_t)n * C_DIM + ch * 128 + cc) * L_DIM + l0 + ll];
        }
        __syncthreads();
        // sumsq partial: thread covers c-slice [w*16, w*16+16) of this chunk for l=lane
#pragma unroll
        for (int i = 0; i < 16; ++i) {
            float v = xs[(w * 16 + i) * 64 + lane];
            ss += v * v;
        }
        // logits partial
        for (int c4 = 0; c4 < 32; ++c4) {
            float xv0 = xs[(c4 * 4 + 0) * 64 + lane];
            float xv1 = xs[(c4 * 4 + 1) * 64 + lane];
            float xv2 = xs[(c4 * 4 + 2) * 64 + lane];
            float xv3 = xs[(c4 * 4 + 3) * 64 + lane];
#pragma unroll
            for (int j = 0; j < 9; ++j) {
                if (j < nk) {
                    int k = w + 8 * j;
                    const float4 w4 = *reinterpret_cast<const float4*>(
                        &conv_w[(size_t)k * C_DIM + ch * 128 + c4 * 4]);
                    acc[j] += w4.x * xv0 + w4.y * xv1 + w4.z * xv2 + w4.w * xv3;
                }
            }
        }
    }

    psum[w * 64 + lane] = ss;
    __syncthreads();
    if (t < 64) {
        float s = 0.f;
#pragma unroll
        for (int p = 0; p < 8; ++p) s += psum[p * 64 + t];
        float nrm = sqrtf(s);
        invl[t] = 1.0f / fmaxf(nrm, 1e-12f);
    }
    __syncthreads();
    const float inv = invl[lane];
#pragma unroll
    for (int j = 0; j < 9; ++j) {
        if (j < nk) {
            int k = w + 8 * j;
            lg[k * 64 + lane] = acc[j] * inv + conv_b[k];
        }
    }
    __syncthreads();
    // softmax over k (65) per position l = t, threads 0..63
    if (t < 64) {
        float m = -1e30f;
        for (int k = 0; k < KG; ++k) m = fmaxf(m, lg[k * 64 + t]);
        float s = 0.f;
        for (int k = 0; k < KG; ++k) {
            float e = expf(lg[k * 64 + t] - m);
            lg[k * 64 + t] = e;
            s += e;
        }
        rsl[t] = 1.0f / s;
    }
    __syncthreads();
    const float rs = rsl[lane];
#pragma unroll
    for (int j = 0; j < 9; ++j) {
        if (j < nk) {
            int k = w + 8 * j;
            if (k < KK) {
                float aval = lg[k * 64 + lane] * rs;    // true a
                // wave-reduce sum over the 64 positions
                float ssum = aval;
#pragma unroll
                for (int off = 32; off; off >>= 1) ssum += __shfl_down(ssum, off, 64);
                if (lane == 0) asum_part[((size_t)n * 16 + lb) * KK + k] = ssum;
                aP[((size_t)n * KK + k) * L_DIM + l0 + lane] = aval * inv;  // a' = a*invnorm
            }
        }
    }
}

// ---------------- a_sum reduce ----------------
__global__ void k_asum(const float* __restrict__ part, float* __restrict__ a_sum)
{
    int id = blockIdx.x * 256 + threadIdx.x;  // 4096 = 64n * 64k
    int n = id >> 6, k = id & 63;
    float s = 0.f;
#pragma unroll
    for (int p = 0; p < 16; ++p) s += part[((size_t)n * 16 + p) * KK + k];
    a_sum[id] = s;
}

// ---------------- Stage 2: weighted[n,k,c] partials over l-quarters ----------------
// Grid: (4 l-quarters, 2 c-tiles, 64 images), Block: 512. Lane owns 4 c's, wave owns 8 k's.
__global__ __launch_bounds__(512) void k_stage2(
    const float* __restrict__ x, const float* __restrict__ aP, float* __restrict__ wpart)
{
    __shared__ float xs[32 * 260];   // [l][c] padded, 33.3 KB
    __shared__ float as[KK * 32];    // [k][l] 8 KB

    const int lq = blockIdx.x;   // 0..3
    const int ct = blockIdx.y;   // 0..1
    const int n  = blockIdx.z;   // 0..63
    const int t = threadIdx.x, lane = t & 63, w = t >> 6;
    const int lbase = lq * 256;
    const int cbase = ct * 256;

    float acc[8][4] = {};

    for (int lc = 0; lc < 8; ++lc) {
        __syncthreads();
        // load x chunk: 256c x 32l (coalesced in l), transpose into [l][c]
#pragma unroll
        for (int i = 0; i < 16; ++i) {
            int idx = i * 512 + t;
            int cc = idx >> 5;      // 0..255
            int ll = idx & 31;
            xs[ll * 260 + cc] =
                x[((size_t)n * C_DIM + cbase + cc) * L_DIM + lbase + lc * 32 + ll];
        }
        // load a' chunk: 64k x 32l
#pragma unroll
        for (int i = 0; i < 4; ++i) {
            int idx = i * 512 + t;
            int kk2 = idx >> 5, ll = idx & 31;
            as[kk2 * 32 + ll] = aP[((size_t)n * KK + kk2) * L_DIM + lbase + lc * 32 + ll];
        }
        __syncthreads();
#pragma unroll
        for (int l4 = 0; l4 < 8; ++l4) {
            float4 av[8];
#pragma unroll
            for (int j = 0; j < 8; ++j)
                av[j] = *reinterpret_cast<const float4*>(&as[(w * 8 + j) * 32 + l4 * 4]);
#pragma unroll
            for (int r = 0; r < 4; ++r) {
                float4 xv = *reinterpret_cast<const float4*>(&xs[(l4 * 4 + r) * 260 + lane * 4]);
#pragma unroll
                for (int j = 0; j < 8; ++j) {
                    float a = (r == 0) ? av[j].x : (r == 1) ? av[j].y : (r == 2) ? av[j].z : av[j].w;
                    acc[j][0] += a * xv.x;
                    acc[j][1] += a * xv.y;
                    acc[j][2] += a * xv.z;
                    acc[j][3] += a * xv.w;
                }
            }
        }
    }
#pragma unroll
    for (int j = 0; j < 8; ++j) {
        int k = w * 8 + j;
        float4 v = make_float4(acc[j][0], acc[j][1], acc[j][2], acc[j][3]);
        *reinterpret_cast<float4*>(
            &wpart[(((size_t)n * 4 + lq) * KK + k) * C_DIM + cbase + lane * 4]) = v;
    }
}

// ---------------- reduce l-quarter partials ----------------
__global__ void k_wreduce(const float* __restrict__ wpart, float* __restrict__ wsum)
{
    size_t id = (size_t)blockIdx.x * 256 + threadIdx.x;  // 64*64*512 = 2,097,152
    size_t n = id >> 15;
    size_t rest = id & 32767;
    float s = 0.f;
#pragma unroll
    for (int q = 0; q < 4; ++q) s += wpart[n * 131072 + (size_t)q * 32768 + rest];
    wsum[id] = s;
}

// ---------------- per-(n,k) row sumsq of vlad ----------------
__global__ void k_rownorm(const float* __restrict__ wsum, const float* __restrict__ a_sum,
                          const float* __restrict__ cent, float* __restrict__ rn)
{
    int nk = blockIdx.x;          // 0..4095
    int k = nk & 63;
    int t = threadIdx.x;          // 256
    float as = a_sum[nk];
    float s = 0.f;
    for (int c = t; c < C_DIM; c += 256) {
        float v = wsum[(size_t)nk * C_DIM + c] - as * cent[(size_t)k * C_DIM + c];
        s += v * v;
    }
#pragma unroll
    for (int off = 32; off; off >>= 1) s += __shfl_down(s, off, 64);
    __shared__ float red[4];
    if ((t & 63) == 0) red[t >> 6] = s;
    __syncthreads();
    if (t == 0) rn[nk] = red[0] + red[1] + red[2] + red[3];
}

// ---------------- per-n global norm -> combined scale ----------------
__global__ void k_scale(const float* __restrict__ rn, float* __restrict__ scale)
{
    int n = blockIdx.x;     // 64
    int k = threadIdx.x;    // 64 = one wave
    float s = rn[n * 64 + k];
    float nrm = sqrtf(s);
    float den = fmaxf(nrm, 1e-12f);
    float tk = nrm / den;               // row-normalized row's norm (0 or 1)
    float tot = tk * tk;
#pragma unroll
    for (int off = 32; off; off >>= 1) tot += __shfl_down(tot, off, 64);
    tot = __shfl(tot, 0, 64);
    float g = fmaxf(sqrtf(tot), 1e-12f);
    scale[n * 64 + k] = 1.0f / (den * g);
}

// ---------------- final output ----------------
__global__ void k_out(const float* __restrict__ wsum, const float* __restrict__ a_sum,
                      const float* __restrict__ cent, const float* __restrict__ scale,
                      float* __restrict__ out)
{
    int nk = blockIdx.x;
    int k = nk & 63;
    int t = threadIdx.x;
    float as = a_sum[nk];
    float sc = scale[nk];
    for (int c = t; c < C_DIM; c += 256) {
        float v = wsum[(size_t)nk * C_DIM + c] - as * cent[(size_t)k * C_DIM + c];
        out[(size_t)nk * C_DIM + c] = v * sc;
    }
}

extern "C" void kernel_launch(void* const* d_in, const int* in_sizes, int n_in,
                              void* d_out, int out_size, void* d_ws, size_t ws_size,
                              hipStream_t stream)
{
    const float* x    = (const float*)d_in[0];
    const float* cent = (const float*)d_in[1];
    const float* cw   = (const float*)d_in[2];
    const float* cb   = (const float*)d_in[3];
    float* out = (float*)d_out;
    float* ws  = (float*)d_ws;

    float* aP        = ws;                                    // 64*64*1024
    float* asum_part = aP + (size_t)64 * 64 * 1024;           // 64*16*64
    float* a_sum     = asum_part + (size_t)64 * 16 * 64;      // 64*64
    float* wpart     = a_sum + 64 * 64;                       // 64*4*64*512
    float* weighted  = wpart + (size_t)64 * 4 * 64 * 512;     // 64*64*512
    float* rn        = weighted + (size_t)64 * 64 * 512;      // 64*64
    float* scale     = rn + 64 * 64;                          // 64*64

    k_stage1<<<dim3(16, 64), 512, 0, stream>>>(x, cw, cb, aP, asum_part);
    k_asum<<<16, 256, 0, stream>>>(asum_part, a_sum);
    k_stage2<<<dim3(4, 2, 64), 512, 0, stream>>>(x, aP, wpart);
    k_wreduce<<<8192, 256, 0, stream>>>(wpart, weighted);
    k_rownorm<<<4096, 256, 0, stream>>>(weighted, a_sum, cent, rn);
    k_scale<<<64, 64, 0, stream>>>(rn, scale);
    k_out<<<4096, 256, 0, stream>>>(weighted, a_sum, cent, scale, out);
}